// Round 2
// baseline (415.299 us; speedup 1.0000x reference)
//
#include <hip/hip_runtime.h>

#define NPTS 16384
#define NB   8
#define NM   2048
#define NC   128
#define EPSF 1e-8f

#define QPW    4                    // queries per wave
#define QPB    16                   // queries per block (4 waves)
#define MAXBPB (NPTS / QPB)         // max blocks per batch segment (1024)

// ws layout
#define FEATST_BYTES ((size_t)NB * NM * NC * sizeof(float))   // 8 MB
#define META_OFF     FEATST_BYTES                             // int offsets[9] @ meta[0..8], cursors @ meta[16..23]
#define PERM_OFF     (FEATST_BYTES + 256)
#define WS_NEED      (PERM_OFF + (size_t)NPTS * sizeof(int))

// lexicographic (d, idx) "better" — matches jax.lax.top_k tie-break (lower idx first)
__device__ __forceinline__ bool better(float d, int i, float dr, int ir) {
    return (d < dr) || ((d == dr) && (i < ir));
}

__device__ __forceinline__ void insert3(float d, int j,
                                        float& d0, int& i0,
                                        float& d1, int& i1,
                                        float& d2, int& i2) {
    if (better(d, j, d2, i2)) {
        if (better(d, j, d1, i1)) {
            if (better(d, j, d0, i0)) {
                d2 = d1; i2 = i1; d1 = d0; i1 = i0; d0 = d; i0 = j;
            } else {
                d2 = d1; i2 = i1; d1 = d; i1 = j;
            }
        } else {
            d2 = d; i2 = j;
        }
    }
}

// (B, C, M) -> (B, M, C) tiled transpose, +1 pad kills bank conflicts
__global__ __launch_bounds__(256) void transpose_feats(const float* __restrict__ in,
                                                       float* __restrict__ out) {
    __shared__ float tile[32][33];
    const int b  = blockIdx.z;
    const int j0 = blockIdx.x * 32;   // M dim
    const int c0 = blockIdx.y * 32;   // C dim
    const int tx = threadIdx.x;       // 32
    const int ty = threadIdx.y;       // 8
#pragma unroll
    for (int i = ty; i < 32; i += 8)
        tile[i][tx] = in[(size_t)b * NC * NM + (size_t)(c0 + i) * NM + (j0 + tx)];
    __syncthreads();
#pragma unroll
    for (int i = ty; i < 32; i += 8)
        out[(size_t)b * NM * NC + (size_t)(j0 + i) * NC + (c0 + tx)] = tile[tx][i];
}

// S1: histogram of batch_inds + exclusive prefix -> offsets[0..8]; cursors[b]=offsets[b]
__global__ __launch_bounds__(256) void seg_offsets(const int* __restrict__ binds,
                                                   int* __restrict__ meta) {
    __shared__ int h[NB];
    const int t = threadIdx.x;
    if (t < NB) h[t] = 0;
    __syncthreads();
    for (int p = t; p < NPTS; p += 256) atomicAdd(&h[binds[p]], 1);
    __syncthreads();
    if (t == 0) {
        int s = 0;
        for (int b = 0; b < NB; ++b) { meta[b] = s; meta[16 + b] = s; s += h[b]; }
        meta[NB] = s;
    }
}

// S2: scatter point ids into per-batch contiguous segments of perm
__global__ __launch_bounds__(256) void scatter_perm(const int* __restrict__ binds,
                                                    int* __restrict__ meta,
                                                    int* __restrict__ perm) {
    const int p = blockIdx.x * 256 + threadIdx.x;
    const int b = binds[p];
    const int slot = atomicAdd(&meta[16 + b], 1);
    perm[slot] = p;
}

// Main: one block per (batch, 16-query chunk). Known points of the batch staged in LDS.
// Each wave handles 4 queries; lane covers known j = it*64+lane (same order as R1 -> bit-identical).
__global__ __launch_bounds__(256) void nn_interp_seg(const float* __restrict__ unknown,
                                                     const float* __restrict__ known,
                                                     const float* __restrict__ featsT,
                                                     const int*   __restrict__ meta,
                                                     const int*   __restrict__ perm,
                                                     float* __restrict__ out) {
    const int b      = blockIdx.y;
    const int segBeg = meta[b];
    const int segEnd = meta[b + 1];
    const int qbase  = segBeg + blockIdx.x * QPB;
    if (qbase >= segEnd) return;   // block-uniform exit, before any __syncthreads

    __shared__ float4 kpt[NM];     // 32 KB, w component unused
    {
        const float* kb  = known + (size_t)b * NM * 3;
        float*       kls = (float*)kpt;
        for (int d = threadIdx.x; d < NM * 3; d += 256) {
            const int j = d / 3;
            const int c = d - j * 3;
            kls[j * 4 + c] = kb[d];
        }
    }
    __syncthreads();

    const int wave = threadIdx.x >> 6;
    const int lane = threadIdx.x & 63;

    float ux[QPW], uy[QPW], uz[QPW];
    int   qp[QPW];
#pragma unroll
    for (int k = 0; k < QPW; ++k) {
        int idx = qbase + wave * QPW + k;
        if (idx >= segEnd) idx = segBeg;          // duplicate of an earlier query: benign
        const int q = perm[idx];
        qp[k] = q;
        ux[k] = unknown[q * 3 + 0];
        uy[k] = unknown[q * 3 + 1];
        uz[k] = unknown[q * 3 + 2];
    }

    float D0[QPW], D1[QPW], D2[QPW];
    int   I0[QPW], I1[QPW], I2[QPW];
#pragma unroll
    for (int k = 0; k < QPW; ++k) {
        D0[k] = D1[k] = D2[k] = __builtin_inff();
        I0[k] = I1[k] = I2[k] = NM;
    }

#pragma unroll 2
    for (int it = 0; it < NM / 64; ++it) {
        const int j = it * 64 + lane;
        const float4 kp = kpt[j];
#pragma unroll
        for (int k = 0; k < QPW; ++k) {
            const float dx = __fsub_rn(ux[k], kp.x);
            const float dy = __fsub_rn(uy[k], kp.y);
            const float dz = __fsub_rn(uz[k], kp.z);
            const float d  = __fadd_rn(__fadd_rn(__fmul_rn(dx, dx), __fmul_rn(dy, dy)),
                                       __fmul_rn(dz, dz));
            insert3(d, j, D0[k], I0[k], D1[k], I1[k], D2[k], I2[k]);
        }
    }

    // per-query shfl_down tree reduce (disjoint sublists every stage — no duplicates)
#pragma unroll
    for (int off = 32; off >= 1; off >>= 1) {
#pragma unroll
        for (int k = 0; k < QPW; ++k) {
            const float e0 = __shfl_down(D0[k], off);
            const float e1 = __shfl_down(D1[k], off);
            const float e2 = __shfl_down(D2[k], off);
            const int   j0 = __shfl_down(I0[k], off);
            const int   j1 = __shfl_down(I1[k], off);
            const int   j2 = __shfl_down(I2[k], off);
            insert3(e0, j0, D0[k], I0[k], D1[k], I1[k], D2[k], I2[k]);
            insert3(e1, j1, D0[k], I0[k], D1[k], I1[k], D2[k], I2[k]);
            insert3(e2, j2, D0[k], I0[k], D1[k], I1[k], D2[k], I2[k]);
        }
    }

    const float* ft = featsT + (size_t)b * NM * NC;
#pragma unroll
    for (int k = 0; k < QPW; ++k) {
        const float d0 = __shfl(D0[k], 0), d1 = __shfl(D1[k], 0), d2 = __shfl(D2[k], 0);
        const int   i0 = __shfl(I0[k], 0), i1 = __shfl(I1[k], 0), i2 = __shfl(I2[k], 0);

        const float t0 = 1.0f / (sqrtf(d0) + EPSF);
        const float t1 = 1.0f / (sqrtf(d1) + EPSF);
        const float t2 = 1.0f / (sqrtf(d2) + EPSF);
        const float s  = t0 + t1 + t2;
        const float w0 = t0 / s, w1 = t1 / s, w2 = t2 / s;

        const float* f0p = ft + (size_t)i0 * NC;
        const float* f1p = ft + (size_t)i1 * NC;
        const float* f2p = ft + (size_t)i2 * NC;
        const int p = qp[k];
#pragma unroll
        for (int c = lane; c < NC; c += 64) {
            out[(size_t)p * NC + c] = w0 * f0p[c] + w1 * f1p[c] + w2 * f2p[c];
        }
    }
}

// ---------------- R1 fallback (used only if ws_size < WS_NEED) ----------------
__global__ __launch_bounds__(256) void nn_interp(const float* __restrict__ unknown,
                                                 const float* __restrict__ known,
                                                 const int*   __restrict__ binds,
                                                 const float* __restrict__ feats,   // (B,C,M)
                                                 const float* __restrict__ featsT,  // (B,M,C)
                                                 float* __restrict__ out,
                                                 int useT) {
    const int wave = threadIdx.x >> 6;
    const int lane = threadIdx.x & 63;
    const int p    = blockIdx.x * 4 + wave;

    const int b = binds[p];
    const float ux = unknown[p * 3 + 0];
    const float uy = unknown[p * 3 + 1];
    const float uz = unknown[p * 3 + 2];

    const float* kb = known + (size_t)b * NM * 3;

    float d0 = __builtin_inff(), d1 = __builtin_inff(), d2 = __builtin_inff();
    int   i0 = NM, i1 = NM, i2 = NM;

#pragma unroll 4
    for (int it = 0; it < NM / 64; ++it) {
        const int j = it * 64 + lane;
        const float kx = kb[j * 3 + 0];
        const float ky = kb[j * 3 + 1];
        const float kz = kb[j * 3 + 2];
        const float dx = __fsub_rn(ux, kx);
        const float dy = __fsub_rn(uy, ky);
        const float dz = __fsub_rn(uz, kz);
        const float d  = __fadd_rn(__fadd_rn(__fmul_rn(dx, dx), __fmul_rn(dy, dy)),
                                   __fmul_rn(dz, dz));
        insert3(d, j, d0, i0, d1, i1, d2, i2);
    }

#pragma unroll
    for (int off = 32; off >= 1; off >>= 1) {
        const float e0 = __shfl_down(d0, off);
        const float e1 = __shfl_down(d1, off);
        const float e2 = __shfl_down(d2, off);
        const int   j0 = __shfl_down(i0, off);
        const int   j1 = __shfl_down(i1, off);
        const int   j2 = __shfl_down(i2, off);
        insert3(e0, j0, d0, i0, d1, i1, d2, i2);
        insert3(e1, j1, d0, i0, d1, i1, d2, i2);
        insert3(e2, j2, d0, i0, d1, i1, d2, i2);
    }
    d0 = __shfl(d0, 0); d1 = __shfl(d1, 0); d2 = __shfl(d2, 0);
    i0 = __shfl(i0, 0); i1 = __shfl(i1, 0); i2 = __shfl(i2, 0);

    const float t0 = 1.0f / (sqrtf(d0) + EPSF);
    const float t1 = 1.0f / (sqrtf(d1) + EPSF);
    const float t2 = 1.0f / (sqrtf(d2) + EPSF);
    const float s  = t0 + t1 + t2;
    const float w0 = t0 / s, w1 = t1 / s, w2 = t2 / s;

    if (useT) {
        const float* ft  = featsT + (size_t)b * NM * NC;
        const float* f0p = ft + (size_t)i0 * NC;
        const float* f1p = ft + (size_t)i1 * NC;
        const float* f2p = ft + (size_t)i2 * NC;
#pragma unroll
        for (int c = lane; c < NC; c += 64) {
            out[(size_t)p * NC + c] = w0 * f0p[c] + w1 * f1p[c] + w2 * f2p[c];
        }
    } else {
        const float* fb = feats + (size_t)b * NC * NM;
#pragma unroll
        for (int c = lane; c < NC; c += 64) {
            const float* fc = fb + (size_t)c * NM;
            out[(size_t)p * NC + c] = w0 * fc[i0] + w1 * fc[i1] + w2 * fc[i2];
        }
    }
}

extern "C" void kernel_launch(void* const* d_in, const int* in_sizes, int n_in,
                              void* d_out, int out_size, void* d_ws, size_t ws_size,
                              hipStream_t stream) {
    const float* unknown = (const float*)d_in[0];   // (n, 3)
    const float* known   = (const float*)d_in[1];   // (B, m, 3)
    const int*   binds   = (const int*)d_in[2];     // (n,)
    const float* feats   = (const float*)d_in[3];   // (B, C, m)
    float*       out     = (float*)d_out;           // (n, C, 1)

    float* featsT = (float*)d_ws;

    if (ws_size >= WS_NEED) {
        int* meta = (int*)((char*)d_ws + META_OFF);
        int* perm = (int*)((char*)d_ws + PERM_OFF);

        dim3 tb(32, 8, 1);
        dim3 tg(NM / 32, NC / 32, NB);
        transpose_feats<<<tg, tb, 0, stream>>>(feats, featsT);
        seg_offsets<<<1, 256, 0, stream>>>(binds, meta);
        scatter_perm<<<NPTS / 256, 256, 0, stream>>>(binds, meta, perm);
        nn_interp_seg<<<dim3(MAXBPB, NB), 256, 0, stream>>>(unknown, known, featsT,
                                                            meta, perm, out);
    } else {
        const int useT = (ws_size >= FEATST_BYTES) ? 1 : 0;
        if (useT) {
            dim3 tb(32, 8, 1);
            dim3 tg(NM / 32, NC / 32, NB);
            transpose_feats<<<tg, tb, 0, stream>>>(feats, featsT);
        }
        nn_interp<<<NPTS / 4, 256, 0, stream>>>(unknown, known, binds, feats, featsT, out, useT);
    }
}

// Round 3
// 163.082 us; speedup vs baseline: 2.5466x; 2.5466x over previous
//
#include <hip/hip_runtime.h>

#define NPTS 16384
#define NB   8
#define NM   2048
#define NC   128
#define EPSF 1e-8f

#define TQ   8                      // threads per query
#define QPB  32                     // queries per 256-thread block
#define BX   68                     // blocks per batch segment (covers >= 2176 queries/batch)

// ws layout
#define FEATST_BYTES ((size_t)NB * NM * NC * sizeof(float))   // 8 MB
#define META_OFF     FEATST_BYTES                             // offsets[0..8] @ meta[0..8], cursors @ meta[16..23]
#define PERM_OFF     (FEATST_BYTES + 256)
#define WS_NEED      (PERM_OFF + (size_t)NPTS * sizeof(int))

// lexicographic (d, idx) "better" — matches jax.lax.top_k tie-break (lower idx first)
__device__ __forceinline__ bool better(float d, int i, float dr, int ir) {
    return (d < dr) || ((d == dr) && (i < ir));
}

// hybrid: cheap guard (usually false after warmup), branchless shift inside
__device__ __forceinline__ void insert3(float d, int j,
                                        float& d0, int& i0,
                                        float& d1, int& i1,
                                        float& d2, int& i2) {
    if (better(d, j, d2, i2)) {
        const bool b0 = better(d, j, d0, i0);
        const bool b1 = better(d, j, d1, i1);
        // b0 => b1 => (guard true)
        d2 = b1 ? d1 : d;  i2 = b1 ? i1 : j;
        d1 = b0 ? d0 : (b1 ? d : d1);
        i1 = b0 ? i0 : (b1 ? j : i1);
        d0 = b0 ? d  : d0; i0 = b0 ? j : i0;
    }
}

// (B, C, M) -> (B, M, C) tiled transpose, +1 pad kills bank conflicts
__global__ __launch_bounds__(256) void transpose_feats(const float* __restrict__ in,
                                                       float* __restrict__ out) {
    __shared__ float tile[32][33];
    const int b  = blockIdx.z;
    const int j0 = blockIdx.x * 32;   // M dim
    const int c0 = blockIdx.y * 32;   // C dim
    const int tx = threadIdx.x;       // 32
    const int ty = threadIdx.y;       // 8
#pragma unroll
    for (int i = ty; i < 32; i += 8)
        tile[i][tx] = in[(size_t)b * NC * NM + (size_t)(c0 + i) * NM + (j0 + tx)];
    __syncthreads();
#pragma unroll
    for (int i = ty; i < 32; i += 8)
        out[(size_t)b * NM * NC + (size_t)(j0 + i) * NC + (c0 + tx)] = tile[tx][i];
}

// S1: histogram (register-private + wave-reduced) + exclusive prefix
__global__ __launch_bounds__(256) void seg_offsets(const int* __restrict__ binds,
                                                   int* __restrict__ meta) {
    __shared__ int h[NB];
    const int t = threadIdx.x;
    if (t < NB) h[t] = 0;
    __syncthreads();
    int cnt[NB];
#pragma unroll
    for (int bb = 0; bb < NB; ++bb) cnt[bb] = 0;
    for (int p = t; p < NPTS; p += 256) {
        const int b = binds[p];
#pragma unroll
        for (int bb = 0; bb < NB; ++bb) cnt[bb] += (b == bb) ? 1 : 0;
    }
#pragma unroll
    for (int bb = 0; bb < NB; ++bb) {
        int v = cnt[bb];
#pragma unroll
        for (int off = 32; off >= 1; off >>= 1) v += __shfl_down(v, off);
        if ((t & 63) == 0) atomicAdd(&h[bb], v);
    }
    __syncthreads();
    if (t == 0) {
        int s = 0;
        for (int b = 0; b < NB; ++b) { meta[b] = s; meta[16 + b] = s; s += h[b]; }
        meta[NB] = s;
    }
}

// S2: scatter point ids into per-batch segments; wave-aggregated atomics (8/wave max)
__global__ __launch_bounds__(256) void scatter_perm(const int* __restrict__ binds,
                                                    int* __restrict__ meta,
                                                    int* __restrict__ perm) {
    const int p = blockIdx.x * 256 + threadIdx.x;
    const int b = binds[p];
    const int lane = threadIdx.x & 63;
    const unsigned long long lt = (lane == 0) ? 0ull : ((~0ull) >> (64 - lane));
#pragma unroll
    for (int bb = 0; bb < NB; ++bb) {
        const unsigned long long mask = __ballot(b == bb);
        if (b == bb) {
            const int leader = __ffsll((long long)mask) - 1;
            int base = 0;
            if (lane == leader) base = atomicAdd(&meta[16 + bb], __popcll(mask));
            base = __shfl(base, leader);
            perm[base + __popcll(mask & lt)] = p;
        }
    }
}

// Main: one block per (batch, 32-query chunk); batch's points staged once in LDS.
// 8 threads per query, thread t scans j = 8i+t (broadcast LDS reads, conflict-free),
// 3-stage intra-group merge. Lexicographic selection is partition-invariant ->
// result identical to sequential scan -> identical to reference top_k.
__global__ __launch_bounds__(256) void nn_interp_seg(const float* __restrict__ unknown,
                                                     const float* __restrict__ featsT,
                                                     const float* __restrict__ known,
                                                     const int*   __restrict__ meta,
                                                     const int*   __restrict__ perm,
                                                     float* __restrict__ out) {
    const int b      = blockIdx.y;
    const int segBeg = meta[b];
    const int segEnd = meta[b + 1];
    if (segBeg + blockIdx.x * QPB >= segEnd) return;   // block-uniform, before syncthreads

    __shared__ float4 kpt[NM];     // 32 KB, w unused
    {
        const float* kb  = known + (size_t)b * NM * 3;
        float*       kls = (float*)kpt;
        for (int d = threadIdx.x; d < NM * 3; d += 256) {
            const int j = d / 3;
            const int c = d - j * 3;
            kls[j * 4 + c] = kb[d];
        }
    }
    __syncthreads();

    const int qi   = threadIdx.x >> 3;   // query within block, 0..31
    const int t    = threadIdx.x & 7;    // thread within query group
    const int lane = threadIdx.x & 63;

    const float4* ftb = (const float4*)(featsT + (size_t)b * NM * NC);

    for (int qb = segBeg + blockIdx.x * QPB; qb < segEnd; qb += BX * QPB) {
        int idx = qb + qi;
        if (idx >= segEnd) idx = segBeg;      // duplicate of an earlier query: benign race, same bytes
        const int p = perm[idx];
        const float ux = unknown[p * 3 + 0];
        const float uy = unknown[p * 3 + 1];
        const float uz = unknown[p * 3 + 2];

        float d0 = __builtin_inff(), d1 = __builtin_inff(), d2 = __builtin_inff();
        int   i0 = NM, i1 = NM, i2 = NM;

#pragma unroll 4
        for (int i = 0; i < NM / TQ; ++i) {
            const int j = (i << 3) | t;
            const float4 kp = kpt[j];
            const float dx = __fsub_rn(ux, kp.x);
            const float dy = __fsub_rn(uy, kp.y);
            const float dz = __fsub_rn(uz, kp.z);
            const float d  = __fadd_rn(__fadd_rn(__fmul_rn(dx, dx), __fmul_rn(dy, dy)),
                                       __fmul_rn(dz, dz));
            insert3(d, j, d0, i0, d1, i1, d2, i2);
        }

        // merge 8 partial top-3 lists within the group (shfl_down: disjoint partners,
        // valid chain lands at t=0), then broadcast from group base lane
#pragma unroll
        for (int off = 4; off >= 1; off >>= 1) {
            const float e0 = __shfl_down(d0, off);
            const float e1 = __shfl_down(d1, off);
            const float e2 = __shfl_down(d2, off);
            const int   j0 = __shfl_down(i0, off);
            const int   j1 = __shfl_down(i1, off);
            const int   j2 = __shfl_down(i2, off);
            insert3(e0, j0, d0, i0, d1, i1, d2, i2);
            insert3(e1, j1, d0, i0, d1, i1, d2, i2);
            insert3(e2, j2, d0, i0, d1, i1, d2, i2);
        }
        const int src = lane & ~7;
        d0 = __shfl(d0, src); d1 = __shfl(d1, src); d2 = __shfl(d2, src);
        i0 = __shfl(i0, src); i1 = __shfl(i1, src); i2 = __shfl(i2, src);

        const float t0 = 1.0f / (sqrtf(d0) + EPSF);
        const float t1 = 1.0f / (sqrtf(d1) + EPSF);
        const float t2 = 1.0f / (sqrtf(d2) + EPSF);
        const float s  = t0 + t1 + t2;
        const float w0 = t0 / s, w1 = t1 / s, w2 = t2 / s;

        const float4* f0 = ftb + (size_t)i0 * (NC / 4);
        const float4* f1 = ftb + (size_t)i1 * (NC / 4);
        const float4* f2 = ftb + (size_t)i2 * (NC / 4);
        float4* o4 = (float4*)(out + (size_t)p * NC);
#pragma unroll
        for (int k = 0; k < 4; ++k) {
            const int c4 = t + k * 8;          // 8 lanes cover one 128B run
            const float4 a = f0[c4], bb4 = f1[c4], c = f2[c4];
            float4 r;
            r.x = w0 * a.x + w1 * bb4.x + w2 * c.x;
            r.y = w0 * a.y + w1 * bb4.y + w2 * c.y;
            r.z = w0 * a.z + w1 * bb4.z + w2 * c.z;
            r.w = w0 * a.w + w1 * bb4.w + w2 * c.w;
            o4[c4] = r;
        }
    }
}

// ---------------- fallback (only if ws too small; R2 proved it isn't) ----------------
__global__ __launch_bounds__(256) void nn_interp(const float* __restrict__ unknown,
                                                 const float* __restrict__ known,
                                                 const int*   __restrict__ binds,
                                                 const float* __restrict__ feats,
                                                 float* __restrict__ out) {
    const int wave = threadIdx.x >> 6;
    const int lane = threadIdx.x & 63;
    const int p    = blockIdx.x * 4 + wave;

    const int b = binds[p];
    const float ux = unknown[p * 3 + 0];
    const float uy = unknown[p * 3 + 1];
    const float uz = unknown[p * 3 + 2];
    const float* kb = known + (size_t)b * NM * 3;

    float d0 = __builtin_inff(), d1 = __builtin_inff(), d2 = __builtin_inff();
    int   i0 = NM, i1 = NM, i2 = NM;
#pragma unroll 4
    for (int it = 0; it < NM / 64; ++it) {
        const int j = it * 64 + lane;
        const float dx = __fsub_rn(ux, kb[j * 3 + 0]);
        const float dy = __fsub_rn(uy, kb[j * 3 + 1]);
        const float dz = __fsub_rn(uz, kb[j * 3 + 2]);
        const float d  = __fadd_rn(__fadd_rn(__fmul_rn(dx, dx), __fmul_rn(dy, dy)),
                                   __fmul_rn(dz, dz));
        insert3(d, j, d0, i0, d1, i1, d2, i2);
    }
#pragma unroll
    for (int off = 32; off >= 1; off >>= 1) {
        const float e0 = __shfl_down(d0, off);
        const float e1 = __shfl_down(d1, off);
        const float e2 = __shfl_down(d2, off);
        const int   j0 = __shfl_down(i0, off);
        const int   j1 = __shfl_down(i1, off);
        const int   j2 = __shfl_down(i2, off);
        insert3(e0, j0, d0, i0, d1, i1, d2, i2);
        insert3(e1, j1, d0, i0, d1, i1, d2, i2);
        insert3(e2, j2, d0, i0, d1, i1, d2, i2);
    }
    d0 = __shfl(d0, 0); d1 = __shfl(d1, 0); d2 = __shfl(d2, 0);
    i0 = __shfl(i0, 0); i1 = __shfl(i1, 0); i2 = __shfl(i2, 0);

    const float t0 = 1.0f / (sqrtf(d0) + EPSF);
    const float t1 = 1.0f / (sqrtf(d1) + EPSF);
    const float t2 = 1.0f / (sqrtf(d2) + EPSF);
    const float s  = t0 + t1 + t2;
    const float w0 = t0 / s, w1 = t1 / s, w2 = t2 / s;

    const float* fb = feats + (size_t)b * NC * NM;
#pragma unroll
    for (int c = lane; c < NC; c += 64) {
        const float* fc = fb + (size_t)c * NM;
        out[(size_t)p * NC + c] = w0 * fc[i0] + w1 * fc[i1] + w2 * fc[i2];
    }
}

extern "C" void kernel_launch(void* const* d_in, const int* in_sizes, int n_in,
                              void* d_out, int out_size, void* d_ws, size_t ws_size,
                              hipStream_t stream) {
    const float* unknown = (const float*)d_in[0];   // (n, 3)
    const float* known   = (const float*)d_in[1];   // (B, m, 3)
    const int*   binds   = (const int*)d_in[2];     // (n,)
    const float* feats   = (const float*)d_in[3];   // (B, C, m)
    float*       out     = (float*)d_out;           // (n, C, 1)

    if (ws_size >= WS_NEED) {
        float* featsT = (float*)d_ws;
        int*   meta   = (int*)((char*)d_ws + META_OFF);
        int*   perm   = (int*)((char*)d_ws + PERM_OFF);

        dim3 tb(32, 8, 1);
        dim3 tg(NM / 32, NC / 32, NB);
        transpose_feats<<<tg, tb, 0, stream>>>(feats, featsT);
        seg_offsets<<<1, 256, 0, stream>>>(binds, meta);
        scatter_perm<<<NPTS / 256, 256, 0, stream>>>(binds, meta, perm);
        nn_interp_seg<<<dim3(BX, NB), 256, 0, stream>>>(unknown, featsT, known,
                                                        meta, perm, out);
    } else {
        nn_interp<<<NPTS / 4, 256, 0, stream>>>(unknown, known, binds, feats, out);
    }
}

// Round 5
// 140.353 us; speedup vs baseline: 2.9590x; 1.1619x over previous
//
#include <hip/hip_runtime.h>

#define NPTS 16384
#define NB   8
#define NM   2048
#define NC   128
#define EPSF 1e-8f

#define TQ   16                     // threads per query
#define QPB  16                     // queries per 256-thread block
#define GX   128                    // blocks per batch; grid = 1024 = 4/CU exactly

// u64 key = (float_bits(d) << 32) | j : for d >= 0, u64 '<' == lexicographic (d, idx) '<'
#define MERGE_KEY(e) do {                              \
    if ((e) < K2) {                                    \
        const bool _b1 = (e) < K1;                     \
        const bool _b0 = (e) < K0;                     \
        K2 = _b1 ? K1 : (e);                           \
        K1 = _b0 ? K0 : (_b1 ? (e) : K1);              \
        K0 = _b0 ? (e) : K0;                           \
    } } while (0)

// ONE dispatch, no workspace, no cross-block dependencies.
// Each block: (batch b = blockIdx.y, window x = blockIdx.x)
//   - stages batch b's 2048 known points into LDS (32 KB)
//   - scans binds to find the query ids of ranks [x*16, x*16+16) of batch b
//     (stable order -> identical to a global stable bucket sort)
//   - 3-NN (u64 keys, TQ=16 threads/query) + interpolation from raw (B,C,m) feats
__global__ __launch_bounds__(256, 4) void fused(const float* __restrict__ unknown,
                                                const float* __restrict__ known,
                                                const int*   __restrict__ binds,
                                                const float* __restrict__ feats,
                                                float* __restrict__ out) {
    __shared__ float4 kpt[NM];      // 32 KB, w unused
    __shared__ int qlist[QPB];
    __shared__ int wsum[4];

    const int tid  = threadIdx.x;
    const int b    = blockIdx.y;
    const int x    = blockIdx.x;
    const int lane = tid & 63;
    const int wave = tid >> 6;

    // ---- stage known points of batch b into LDS ----
    {
        const float* kb  = known + (size_t)b * NM * 3;
        float*       kls = (float*)kpt;
        for (int d = tid; d < NM * 3; d += 256) {
            const int j = d / 3;
            const int c = d - j * 3;
            kls[j * 4 + c] = kb[d];
        }
    }

    // ---- block-local scan: count matches of batch b, exclusive prefix over 256 threads ----
    const int4* b4 = (const int4*)binds;   // thread t owns binds[t*64 .. t*64+63]
    int myCnt = 0;
#pragma unroll
    for (int r = 0; r < 16; ++r) {
        const int4 v = b4[tid * 16 + r];
        myCnt += (v.x == b) + (v.y == b) + (v.z == b) + (v.w == b);
    }
    int inc = myCnt;                       // intra-wave inclusive prefix
#pragma unroll
    for (int off = 1; off <= 32; off <<= 1) {
        const int n = __shfl_up(inc, off);
        if (lane >= off) inc += n;
    }
    if (lane == 63) wsum[wave] = inc;
    __syncthreads();                       // covers kpt staging + wsum
    int wbase = 0;
    for (int w = 0; w < wave; ++w) wbase += wsum[w];
    const int exPre = wbase + inc - myCnt; // global exclusive prefix (rank of my first match)
    const int segN  = wsum[0] + wsum[1] + wsum[2] + wsum[3];

    const int qi = tid >> 4;   // query within block, 0..15
    const int t  = tid & 15;   // thread within query group

    // ---- window loop (uniform condition; mop-up covers segN > GX*QPB) ----
    for (int w0 = x * QPB; w0 < segN; w0 += GX * QPB) {
        __syncthreads();       // previous window's qlist reads complete
        // extraction: threads whose rank range intersects [w0, w0+QPB) rescan their 64 binds
        if (exPre < w0 + QPB && exPre + myCnt > w0) {
            int rank = exPre;
#pragma unroll
            for (int r = 0; r < 16; ++r) {
                const int4 v = b4[tid * 16 + r];
                const int base = tid * 64 + r * 4;
                if (v.x == b) { if (rank >= w0 && rank < w0 + QPB) qlist[rank - w0] = base + 0; ++rank; }
                if (v.y == b) { if (rank >= w0 && rank < w0 + QPB) qlist[rank - w0] = base + 1; ++rank; }
                if (v.z == b) { if (rank >= w0 && rank < w0 + QPB) qlist[rank - w0] = base + 2; ++rank; }
                if (v.w == b) { if (rank >= w0 && rank < w0 + QPB) qlist[rank - w0] = base + 3; ++rank; }
            }
        }
        __syncthreads();

        const int valid = (segN - w0 < QPB) ? (segN - w0) : QPB;
        const int kq    = (qi < valid) ? qi : 0;   // duplicate query -> identical bytes, benign
        const int p     = qlist[kq];
        const float ux = unknown[p * 3 + 0];
        const float uy = unknown[p * 3 + 1];
        const float uz = unknown[p * 3 + 2];

        unsigned long long K0 = ~0ull, K1 = ~0ull, K2 = ~0ull;

#pragma unroll 4
        for (int i = 0; i < NM / TQ; ++i) {
            const int j = (i << 4) | t;
            const float4 kp = kpt[j];
            // strict rn, numpy association ((dx2+dy2)+dz2): selection bit-identical to ref
            const float dx = __fsub_rn(ux, kp.x);
            const float dy = __fsub_rn(uy, kp.y);
            const float dz = __fsub_rn(uz, kp.z);
            const float d  = __fadd_rn(__fadd_rn(__fmul_rn(dx, dx), __fmul_rn(dy, dy)),
                                       __fmul_rn(dz, dz));
            const unsigned long long key =
                ((unsigned long long)__float_as_uint(d) << 32) | (unsigned)j;
            MERGE_KEY(key);
        }

        // merge 16 partial top-3 lists (shfl_down tree; valid at group lane 0), broadcast
#pragma unroll
        for (int off = 8; off >= 1; off >>= 1) {
            const unsigned long long e0 = __shfl_down(K0, off);
            const unsigned long long e1 = __shfl_down(K1, off);
            const unsigned long long e2 = __shfl_down(K2, off);
            MERGE_KEY(e0);
            MERGE_KEY(e1);
            MERGE_KEY(e2);
        }
        const int src = lane & ~15;
        K0 = __shfl(K0, src); K1 = __shfl(K1, src); K2 = __shfl(K2, src);

        const float d0 = __uint_as_float((unsigned)(K0 >> 32));
        const float d1 = __uint_as_float((unsigned)(K1 >> 32));
        const float d2 = __uint_as_float((unsigned)(K2 >> 32));
        const int   i0 = (int)(unsigned)K0;
        const int   i1 = (int)(unsigned)K1;
        const int   i2 = (int)(unsigned)K2;

        const float t0 = 1.0f / (sqrtf(d0) + EPSF);
        const float t1 = 1.0f / (sqrtf(d1) + EPSF);
        const float t2 = 1.0f / (sqrtf(d2) + EPSF);
        const float s  = t0 + t1 + t2;
        const float w0w = t0 / s, w1w = t1 / s, w2w = t2 / s;

        // gather from raw (B,C,m): column reads, L2/L3-resident (feats = 8 MB)
        const float* fb = feats + (size_t)b * NC * NM;
#pragma unroll
        for (int k = 0; k < 8; ++k) {
            const int c = t + (k << 4);            // 16 lanes -> 64B-coalesced out rows
            const float* fc = fb + (size_t)c * NM;
            const float f0 = fc[i0];
            const float f1 = fc[i1];
            const float f2 = fc[i2];
            out[(size_t)p * NC + c] = w0w * f0 + w1w * f1 + w2w * f2;
        }
    }
}

extern "C" void kernel_launch(void* const* d_in, const int* in_sizes, int n_in,
                              void* d_out, int out_size, void* d_ws, size_t ws_size,
                              hipStream_t stream) {
    const float* unknown = (const float*)d_in[0];   // (n, 3)
    const float* known   = (const float*)d_in[1];   // (B, m, 3)
    const int*   binds   = (const int*)d_in[2];     // (n,)
    const float* feats   = (const float*)d_in[3];   // (B, C, m)
    float*       out     = (float*)d_out;           // (n, C, 1)

    fused<<<dim3(GX, NB), 256, 0, stream>>>(unknown, known, binds, feats, out);
}

// Round 6
// 112.637 us; speedup vs baseline: 3.6870x; 1.2461x over previous
//
#include <hip/hip_runtime.h>

#define NPTS 16384
#define NB   8
#define NM   2048
#define NC   128
#define EPSF 1e-8f

#define TQ   16                     // threads per query
#define QPB  16                     // queries per 256-thread block
#define GX   160                    // blocks per batch: 2560 query slots >> segN(~2100) -> no tail

// u64 key = (float_bits(d) << 32) | j : for d >= 0, u64 '<' == lexicographic (d, idx) '<'
// Fully branchless: wave-any-update probability is ~1 for i<200, so a guard branch is
// always taken anyway and only adds exec-mask churn + blocks ds_read pipelining (R5 lesson).
#define MERGE_KEY(e) do {                               \
    const bool _b2 = (e) < K2;                          \
    const bool _b1 = (e) < K1;                          \
    const bool _b0 = (e) < K0;                          \
    K2 = _b1 ? K1 : (_b2 ? (e) : K2);                   \
    K1 = _b0 ? K0 : (_b1 ? (e) : K1);                   \
    K0 = _b0 ? (e) : K0;                                \
} while (0)

// ONE dispatch, no workspace, no cross-block dependencies.
// Block (batch b, window x): scan binds -> ranks; exit if window empty; stage batch b's
// points in LDS (SoA float2+float, 24 KB); 3-NN u64-keys TQ=16; gather from raw (B,C,m).
__global__ __launch_bounds__(256, 5) void fused(const float* __restrict__ unknown,
                                                const float* __restrict__ known,
                                                const int*   __restrict__ binds,
                                                const float* __restrict__ feats,
                                                float* __restrict__ out) {
    __shared__ float2 kxy[NM];      // 16 KB
    __shared__ float  kz[NM];       // 8 KB
    __shared__ int qlist[QPB];
    __shared__ int wsum[4];

    const int tid  = threadIdx.x;
    const int b    = blockIdx.y;
    const int x    = blockIdx.x;
    const int lane = tid & 63;
    const int wave = tid >> 6;

    // ---- scan binds: per-thread count of batch-b points, 256-thread exclusive prefix ----
    const int4* b4 = (const int4*)binds;   // thread t owns binds[t*64 .. t*64+63]
    int myCnt = 0;
#pragma unroll
    for (int r = 0; r < 16; ++r) {
        const int4 v = b4[tid * 16 + r];
        myCnt += (v.x == b) + (v.y == b) + (v.z == b) + (v.w == b);
    }
    int inc = myCnt;
#pragma unroll
    for (int off = 1; off <= 32; off <<= 1) {
        const int n = __shfl_up(inc, off);
        if (lane >= off) inc += n;
    }
    if (lane == 63) wsum[wave] = inc;
    __syncthreads();
    int wbase = 0;
    for (int w = 0; w < wave; ++w) wbase += wsum[w];
    const int exPre = wbase + inc - myCnt;
    const int segN  = wsum[0] + wsum[1] + wsum[2] + wsum[3];

    if (x * QPB >= segN) return;           // block-uniform early exit (most extra blocks)

    // ---- stage known points of batch b into LDS (SoA) ----
    {
        const float* kb = known + (size_t)b * NM * 3;
        for (int j = tid; j < NM; j += 256) {
            float2 xy; xy.x = kb[j * 3 + 0]; xy.y = kb[j * 3 + 1];
            kxy[j] = xy;
            kz[j]  = kb[j * 3 + 2];
        }
    }

    const int qi = tid >> 4;   // query within block, 0..15
    const int t  = tid & 15;   // thread within query group

    // ---- window loop (executes once for GX*QPB >= segN; mop-up kept as safety net) ----
    for (int w0 = x * QPB; w0 < segN; w0 += GX * QPB) {
        __syncthreads();       // staging complete / previous window's qlist reads done
        if (exPre < w0 + QPB && exPre + myCnt > w0) {
            int rank = exPre;
#pragma unroll
            for (int r = 0; r < 16; ++r) {
                const int4 v = b4[tid * 16 + r];
                const int base = tid * 64 + r * 4;
                if (v.x == b) { if (rank >= w0 && rank < w0 + QPB) qlist[rank - w0] = base + 0; ++rank; }
                if (v.y == b) { if (rank >= w0 && rank < w0 + QPB) qlist[rank - w0] = base + 1; ++rank; }
                if (v.z == b) { if (rank >= w0 && rank < w0 + QPB) qlist[rank - w0] = base + 2; ++rank; }
                if (v.w == b) { if (rank >= w0 && rank < w0 + QPB) qlist[rank - w0] = base + 3; ++rank; }
            }
        }
        __syncthreads();

        const int valid = (segN - w0 < QPB) ? (segN - w0) : QPB;
        const int kq    = (qi < valid) ? qi : 0;   // duplicate query -> identical bytes, benign
        const int p     = qlist[kq];
        const float ux = unknown[p * 3 + 0];
        const float uy = unknown[p * 3 + 1];
        const float uz = unknown[p * 3 + 2];

        unsigned long long K0 = ~0ull, K1 = ~0ull, K2 = ~0ull;

#pragma unroll 8
        for (int i = 0; i < NM / TQ; ++i) {
            const int j = (i << 4) | t;
            const float2 kp = kxy[j];
            const float  kzz = kz[j];
            // strict rn, numpy association ((dx2+dy2)+dz2): selection bit-identical to ref
            const float dx = __fsub_rn(ux, kp.x);
            const float dy = __fsub_rn(uy, kp.y);
            const float dz = __fsub_rn(uz, kzz);
            const float d  = __fadd_rn(__fadd_rn(__fmul_rn(dx, dx), __fmul_rn(dy, dy)),
                                       __fmul_rn(dz, dz));
            const unsigned long long key =
                ((unsigned long long)__float_as_uint(d) << 32) | (unsigned)j;
            MERGE_KEY(key);
        }

        // merge 16 partial top-3 lists (shfl_down tree; valid at group lane 0), broadcast
#pragma unroll
        for (int off = 8; off >= 1; off >>= 1) {
            const unsigned long long e0 = __shfl_down(K0, off);
            const unsigned long long e1 = __shfl_down(K1, off);
            const unsigned long long e2 = __shfl_down(K2, off);
            MERGE_KEY(e0);
            MERGE_KEY(e1);
            MERGE_KEY(e2);
        }
        const int src = lane & ~15;
        K0 = __shfl(K0, src); K1 = __shfl(K1, src); K2 = __shfl(K2, src);

        const float d0 = __uint_as_float((unsigned)(K0 >> 32));
        const float d1 = __uint_as_float((unsigned)(K1 >> 32));
        const float d2 = __uint_as_float((unsigned)(K2 >> 32));
        const int   i0 = (int)(unsigned)K0;
        const int   i1 = (int)(unsigned)K1;
        const int   i2 = (int)(unsigned)K2;

        const float t0 = 1.0f / (sqrtf(d0) + EPSF);
        const float t1 = 1.0f / (sqrtf(d1) + EPSF);
        const float t2 = 1.0f / (sqrtf(d2) + EPSF);
        const float s  = t0 + t1 + t2;
        const float w0w = t0 / s, w1w = t1 / s, w2w = t2 / s;

        // gather from raw (B,C,m): column reads, L2/L3-resident (feats = 8 MB)
        const float* fb = feats + (size_t)b * NC * NM;
#pragma unroll
        for (int k = 0; k < 8; ++k) {
            const int c = t + (k << 4);            // 16 lanes -> 64B-coalesced out rows
            const float* fc = fb + (size_t)c * NM;
            const float f0 = fc[i0];
            const float f1 = fc[i1];
            const float f2 = fc[i2];
            out[(size_t)p * NC + c] = w0w * f0 + w1w * f1 + w2w * f2;
        }
    }
}

extern "C" void kernel_launch(void* const* d_in, const int* in_sizes, int n_in,
                              void* d_out, int out_size, void* d_ws, size_t ws_size,
                              hipStream_t stream) {
    const float* unknown = (const float*)d_in[0];   // (n, 3)
    const float* known   = (const float*)d_in[1];   // (B, m, 3)
    const int*   binds   = (const int*)d_in[2];     // (n,)
    const float* feats   = (const float*)d_in[3];   // (B, C, m)
    float*       out     = (float*)d_out;           // (n, C, 1)

    fused<<<dim3(GX, NB), 256, 0, stream>>>(unknown, known, binds, feats, out);
}